// Round 1
// baseline (150.183 us; speedup 1.0000x reference)
//
#include <hip/hip_runtime.h>

// MTH spiking-threshold recurrence: elementwise over N = B*C*H*W positions,
// T=4 timesteps, K=8 thresholds. Pure memory-bound streaming kernel.
//
// x layout (flat): [T+1, N] with N = B*C*H*W; plane 0 is the bias.
// out layout:      [T+1, N]; plane 0 = zeros, planes 1..T = spikes.

constexpr int T_STEPS = 4;
constexpr int K_THR   = 8;

__global__ __launch_bounds__(256) void mth_kernel(
    const float* __restrict__ x, const float* __restrict__ thresh,
    float* __restrict__ out, int n4)
{
    const float th = thresh[0];
    const int i = blockIdx.x * blockDim.x + threadIdx.x;
    if (i >= n4) return;

    const float4* __restrict__ xv = reinterpret_cast<const float4*>(x);
    float4* __restrict__ ov       = reinterpret_cast<float4*>(out);

    const float4 b4 = xv[i];
    // plane 0 of output is zeros (harness poisons d_out with 0xAA)
    ov[i] = make_float4(0.f, 0.f, 0.f, 0.f);

    float b[4]    = {b4.x, b4.y, b4.z, b4.w};
    float mem[4]  = {0.f, 0.f, 0.f, 0.f};
    float cum[4]  = {0.f, 0.f, 0.f, 0.f};
    float ein[4]  = {b4.x, b4.y, b4.z, b4.w};  // exp_in starts at bias
    float eout[4] = {0.f, 0.f, 0.f, 0.f};

    #pragma unroll
    for (int t = 0; t < T_STEPS; ++t) {
        const float4 x4 = xv[(size_t)(t + 1) * n4 + i];
        const float xt[4] = {x4.x, x4.y, x4.z, x4.w};
        const float denom = (float)(t + 1);  // t starts at 0 -> denom = t+1
        float sp[4];

        #pragma unroll
        for (int j = 0; j < 4; ++j) {
            // mem = mem + xt - bias + exp_in - exp_out   (exact ref op order)
            mem[j] = mem[j] + xt[j] - b[j] + ein[j] - eout[j];
            cum[j] = cum[j] + eout[j];

            // diff-of-indicators spike: pos/neg monotone in k, so at most one
            // nonzero term each; exact fp32 either way.
            float spike = 0.f, pos_prev = 0.f, neg_prev = 0.f;
            #pragma unroll
            for (int k = 0; k < K_THR; ++k) {
                const float thre = th * (1.0f / (float)(1 << k));  // exact: th * 2^-k
                const float tt   = 0.75f * thre;
                const float pos  = (mem[j] >= tt) ? 1.f : 0.f;
                const float neg  = (mem[j] <= -tt && cum[j] >= thre) ? 1.f : 0.f;
                spike = spike + thre * (pos - pos_prev) - thre * (neg - neg_prev);
                pos_prev = pos;
                neg_prev = neg;
            }

            mem[j]  = mem[j] - spike;
            cum[j]  = cum[j] + spike;
            ein[j]  = ein[j] + (xt[j] - b[j]) / denom;  // IEEE div, matches np
            eout[j] = eout[j] + spike / denom;
            sp[j]   = spike;
        }

        ov[(size_t)(t + 1) * n4 + i] = make_float4(sp[0], sp[1], sp[2], sp[3]);
    }
}

extern "C" void kernel_launch(void* const* d_in, const int* in_sizes, int n_in,
                              void* d_out, int out_size, void* d_ws, size_t ws_size,
                              hipStream_t stream)
{
    const float* x      = (const float*)d_in[0];
    const float* thresh = (const float*)d_in[1];
    float* out          = (float*)d_out;

    const int N  = in_sizes[0] / (T_STEPS + 1);  // elements per timestep plane
    const int n4 = N / 4;                         // N = 4,194,304 -> divisible by 4

    const int block = 256;
    const int grid  = (n4 + block - 1) / block;   // 4096 blocks
    mth_kernel<<<grid, block, 0, stream>>>(x, thresh, out, n4);
}